// Round 12
// baseline (34.053 us; speedup 1.0000x reference)
//
#include <hip/hip_runtime.h>

#define G 64
#define TT 4096
#define EDGES 131072
#define HALF 65536

#define OUT_ETOT 0
#define OUT_NODEE 64
#define OUT_Q (64 + 4096)
#define OUT_NF (64 + 4096 + 4096)

typedef unsigned long long ull;

__device__ __forceinline__ float wave_sum_f(float v) {
#pragma unroll
    for (int m = 1; m < 64; m <<= 1) v += __shfl_xor(v, m);
    return v;
}
__device__ __forceinline__ double wave_sum_d(double v) {
#pragma unroll
    for (int m = 1; m < 64; m <<= 1) v += __shfl_xor(v, m);
    return v;
}
__device__ __forceinline__ double bcast_d(double v, int j) {
    union { double d; int i[2]; } u;
    u.d = v;
    union { int i[2]; double d; } r;
    r.i[0] = __builtin_amdgcn_readlane(u.i[0], j);
    r.i[1] = __builtin_amdgcn_readlane(u.i[1], j);
    return r.d;
}
__device__ __forceinline__ int type_of(float4 na) {
    int t = 0;
    float best = na.x;
    if (na.y > best) { best = na.y; t = 1; }
    if (na.z > best) { best = na.z; t = 2; }
    if (na.w > best) { best = na.w; t = 3; }
    return t;
}
__device__ __forceinline__ float fcut(float R, float c1) {
    if (R < 1.0f) return c1;             // R is always > 0 here
    if (R > 6.0f) return 0.0f;
    float x = 1.0f - (R - 1.0f) * 0.2f;  // in [0,1]
    float ex = __expf(2.0f * x);
    float t = (ex - 1.0f) / (ex + 1.0f); // tanh(x)
    return t * t * t;
}

// ---- k_part1 (64 blocks x 1024): scan -> factor tril -> fp64 solve ----------
// Phase A: zero LDS packed table; Phase B: vectorized edge scan (LDS atomicMax,
// tag = edge idx, mirror tagged e+HALF == np last-write-wins); Phase C: build
// factor (erf term only) into LDS; Phase D: wave 0 solves the dual lower-
// triangular system in fp64 and writes qc, while waves 1-15 export the packed
// table to global (for k_part2's full-chip recompute) and copy node_feats.
// sum(q)=0 per graph exactly (constraint row) => cross-graph "off" term is
// O(solver eps) and dropped; graphs fully independent.
__global__ __launch_bounds__(1024, 1) void k_part1(
    const int* __restrict__ ei, const float* __restrict__ elen,
    const float* __restrict__ node_attrs, const float* __restrict__ kappa,
    const float* __restrict__ ref_eta, const float* __restrict__ ref_log_sigma,
    const float* __restrict__ short_e, const float* __restrict__ nf_in,
    ull* __restrict__ packed_g, float* __restrict__ qc,
    float* __restrict__ out) {
    __shared__ ull s_pack[4096];   // 32 KB per-graph cell table
    __shared__ float sL[64][65];   // factor (erf term)
    __shared__ float s_diag[64];

    const int g = blockIdx.x;
    const int tid = threadIdx.x;
    const int lane = tid & 63;
    const int wv = tid >> 6;               // 0..15
    const float SQRT_PI = 1.7724538509055159f;

    // ---- phase A: zero packed table; per-lane type/sigma; E_tot init --------
#pragma unroll
    for (int k = 0; k < 4; ++k) s_pack[tid + k * 1024] = 0ull;
    const float4 na = *(const float4*)(node_attrs + ((size_t)((g << 6) + lane) << 2));
    const int tj = type_of(na);
    const float sgj = __expf(ref_log_sigma[tj]);
    if (tid < 64) {                         // wave 0: lane == tid
        s_diag[tid] = ref_eta[tj] + 1.0f / (sgj * SQRT_PI);
    }
    if (tid == 64) out[OUT_ETOT + g] = short_e[g];  // init for k_part2 atomics
    __syncthreads();

    // ---- phase B: vectorized edge scan -> LDS atomicMax ---------------------
    {
        const int4* src4 = (const int4*)ei;
        const int4* dst4 = (const int4*)(ei + EDGES);
        const float4* len4 = (const float4*)elen;
#pragma unroll 4
        for (int b = tid; b < HALF / 4; b += 1024) {
            const int4 si = src4[b];
            const int4 dj = dst4[b];
            const float4 rr = len4[b];
            const int e0 = b << 2;
            int iv[4] = { si.x, si.y, si.z, si.w };
            int jv[4] = { dj.x, dj.y, dj.z, dj.w };
            float Rv[4] = { rr.x, rr.y, rr.z, rr.w };
#pragma unroll
            for (int k = 0; k < 4; ++k) {
                if ((iv[k] >> 6) == g) {
                    const ull rb = (ull)__float_as_uint(Rv[k]);
                    const int e = e0 + k;
                    atomicMax(&s_pack[((iv[k] & 63) << 6) + (jv[k] & 63)],
                              ((ull)(unsigned)e << 32) | rb);
                    atomicMax(&s_pack[((jv[k] & 63) << 6) + (iv[k] & 63)],
                              ((ull)(unsigned)(e + HALF) << 32) | rb);
                }
            }
        }
    }
    __syncthreads();

    // ---- phase C: build factor into LDS (full rows, balanced; no fc/E2b) ----
#pragma unroll
    for (int r = 0; r < 4; ++r) {
        const int row = (wv << 2) + r;
        const ull pk = s_pack[(row << 6) + lane];
        const float sgi = __shfl(sgj, row);
        const float gam = sqrtf(sgi * sgi + sgj * sgj);
        const float R = (pk > 0ull) ? __uint_as_float((unsigned)pk) : 0.5f;
        sL[row][lane] = erff(R * (0.70710678118654752f / gam)) * __frcp_rn(R);
    }
    __syncthreads();

    // ---- phase D: wave 0 solves; waves 1-15 export packed + copy feats ------
    if (wv == 0) {
        const int i = tid;
        double Ld = (double)(s_diag[i] + sL[i][i]);
        double inv = 1.0 / Ld;
        double au = 1.0;
        double av = (double)kappa[(g << 6) + i];
        double my_u = 0.0, my_v = 0.0;
        for (int j = 0; j < 64; ++j) {
            double ij = bcast_d(inv, j);
            double uj = bcast_d(au, j) * ij;
            double vj = bcast_d(av, j) * ij;
            if (i == j) { my_u = uj; my_v = vj; }
            if (i > j) {
                double Lij = (double)sL[i][j];
                au -= Lij * uj;
                av -= Lij * vj;
            }
        }
        double Su = wave_sum_d(my_u);
        double Sv = wave_sum_d(my_v);
        double lam = Sv / Su;  // q = -v + (Sv/Su)u  => sum(q) = 0
        qc[(g << 6) + i] = (float)(-my_v + lam * my_u);
    } else {
        // export packed table (4096 ull) for k_part2's full-chip recompute
        for (int t = tid - 64; t < 4096; t += 960)
            packed_g[((size_t)g << 12) + t] = s_pack[t];
        // node_feats copy: 4096 float2 per graph into stride-130 rows
        for (int t2 = tid - 64; t2 < 4096; t2 += 960) {
            int row = t2 >> 6, c = t2 & 63;
            float2 v = ((const float2*)nf_in)[(((g << 6) + row) << 6) + c];
            *(float2*)(out + OUT_NF + (size_t)((g << 6) + row) * 130 + c * 2) = v;
        }
    }
    // no barrier needed: kernel end flushes all writes before k_part2
}

// ---- k_part2 (1024 blocks x 256): full-chip recompute + matvec + epilogue ---
__global__ __launch_bounds__(256) void k_part2(
    const ull* __restrict__ packed_g, const float* __restrict__ qc,
    const float* __restrict__ node_attrs,
    const float* __restrict__ ref_log_sigma, const float* __restrict__ ref_A,
    const float* __restrict__ ref_B, const float* __restrict__ ref_C,
    const float* __restrict__ ref_D, const float* __restrict__ ref_mu,
    const float* __restrict__ atomic_short, float* __restrict__ out) {
    __shared__ float s_red[4];
    const int wv = threadIdx.x >> 6;
    const int i = blockIdx.x * 4 + wv;                  // node / matrix row
    const int lane = threadIdx.x & 63;                  // column
    const int g = i >> 6;                               // uniform per block
    const int ir = i & 63;
    const float SQRT_PI = 1.7724538509055159f;
    const float th1 = tanhf(1.0f);
    const float c1 = th1 * th1 * th1;

    // independent coalesced loads
    const ull pk = packed_g[((size_t)i << 6) + lane];
    const float qj = qc[(g << 6) + lane];
    const float4 na = *(const float4*)(node_attrs + ((size_t)((g << 6) + lane) << 2));

    const int tj = type_of(na);
    const int ti = __shfl(tj, ir);
    const float sgj = __expf(ref_log_sigma[tj]);
    const float sgi = __shfl(sgj, ir);   // own-row sigma, uniform across wave
    const float gam = sqrtf(sgi * sgi + sgj * sgj);

    const float R = (pk > 0ull) ? __uint_as_float((unsigned)pk) : 0.5f;
    const float rinv = __frcp_rn(R);
    const float factor = erff(R * (0.70710678118654752f / gam)) * rinv;
    const float fc = fcut(R, c1);

    float e = 0.0f;
    if (ir != lane) {
        int t4 = ti * 4 + tj;
        float r2 = rinv * rinv;
        float r6 = r2 * r2 * r2;
        e = (ref_A[t4] * __expf(ref_B[t4] * (ref_mu[t4] - R)) -
             ref_C[t4] * r6 - ref_D[t4] * (r6 * r2)) * fc;
    }
    float p = factor * fc * qj;
    float w = factor * qj;
#pragma unroll
    for (int m = 1; m < 64; m <<= 1) {  // 3 interleaved butterflies
        p += __shfl_xor(p, m);
        w += __shfl_xor(w, m);
        e += __shfl_xor(e, m);
    }
    const float q = __shfl(qj, ir);     // qc[i]

    if (lane == 0) {
        float aE2b = 0.5f * e;
        float coef = 0.5f / (sgi * SQRT_PI);
        float V = w + coef * q;         // cross-graph off term ~ 0 (sum q = 0)
        float aEel = q * V;
        out[OUT_NODEE + i] = aEel + aE2b + atomic_short[i];
        out[OUT_Q + i] = q;
        size_t nfb = OUT_NF + (size_t)i * 130;
        out[nfb + 128] = q;
        out[nfb + 129] = p;
        s_red[wv] = aEel + aE2b;
    }
    __syncthreads();
    if (threadIdx.x == 0) {
        atomicAdd(&out[OUT_ETOT + g],
                  s_red[0] + s_red[1] + s_red[2] + s_red[3]);
    }
}

extern "C" void kernel_launch(void* const* d_in, const int* in_sizes, int n_in,
                              void* d_out, int out_size, void* d_ws, size_t ws_size,
                              hipStream_t stream) {
    const float* node_attrs = (const float*)d_in[1];
    const int* edge_index = (const int*)d_in[2];
    const float* edge_length = (const float*)d_in[3];
    const float* kappa = (const float*)d_in[4];
    const float* node_feats = (const float*)d_in[5];
    const float* ref_eta = (const float*)d_in[6];
    const float* ref_log_sigma = (const float*)d_in[7];
    const float* ref_A = (const float*)d_in[8];
    const float* ref_B = (const float*)d_in[9];
    const float* ref_C = (const float*)d_in[10];
    const float* ref_D = (const float*)d_in[11];
    const float* ref_mu = (const float*)d_in[12];
    const float* short_energy = (const float*)d_in[13];
    const float* atomic_short = (const float*)d_in[14];

    float* out = (float*)d_out;
    ull* packed_g = (ull*)d_ws;                 // 2 MiB
    float* qc = (float*)((char*)d_ws + (2u << 20));  // 16 KiB

    k_part1<<<G, 1024, 0, stream>>>(edge_index, edge_length, node_attrs, kappa,
                                    ref_eta, ref_log_sigma, short_energy,
                                    node_feats, packed_g, qc, out);
    k_part2<<<TT / 4, 256, 0, stream>>>(packed_g, qc, node_attrs,
                                        ref_log_sigma, ref_A, ref_B, ref_C,
                                        ref_D, ref_mu, atomic_short, out);
}

// Round 13
// 31.059 us; speedup vs baseline: 1.0964x; 1.0964x over previous
//
#include <hip/hip_runtime.h>

#define G 64
#define TT 4096
#define EDGES 131072
#define HALF 65536

#define OUT_ETOT 0
#define OUT_NODEE 64
#define OUT_Q (64 + 4096)
#define OUT_NF (64 + 4096 + 4096)

typedef unsigned long long ull;

__device__ __forceinline__ float wave_sum_f(float v) {
#pragma unroll
    for (int m = 1; m < 64; m <<= 1) v += __shfl_xor(v, m);
    return v;
}
__device__ __forceinline__ double wave_sum_d(double v) {
#pragma unroll
    for (int m = 1; m < 64; m <<= 1) v += __shfl_xor(v, m);
    return v;
}
__device__ __forceinline__ double bcast_d(double v, int j) {
    union { double d; int i[2]; } u;
    u.d = v;
    union { int i[2]; double d; } r;
    r.i[0] = __builtin_amdgcn_readlane(u.i[0], j);
    r.i[1] = __builtin_amdgcn_readlane(u.i[1], j);
    return r.d;
}
__device__ __forceinline__ int type_of(float4 na) {
    int t = 0;
    float best = na.x;
    if (na.y > best) { best = na.y; t = 1; }
    if (na.z > best) { best = na.z; t = 2; }
    if (na.w > best) { best = na.w; t = 3; }
    return t;
}
__device__ __forceinline__ float fcut(float R, float c1) {
    if (R < 1.0f) return c1;             // R is always > 0 here
    if (R > 6.0f) return 0.0f;
    float x = 1.0f - (R - 1.0f) * 0.2f;  // in [0,1]
    float ex = __expf(2.0f * x);
    float t = (ex - 1.0f) / (ex + 1.0f); // tanh(x)
    return t * t * t;
}

// One block per graph; single dispatch. Phases:
//  A: zero LDS packed table
//  B: edge scan streaming ONLY src (int4); dst/elen gathered on predicate hit
//     (~1/64 edges). LDS atomicMax(tag=edge idx; mirror tagged e+HALF) ==
//     np last-write-wins semantics.
//  C: build factor / factor*Fc in LDS + E2b row sums (16 waves)
//  D: wave 0: fp64 dual forward substitution; waves 1-15: node_feats copy
//  E: matvec row sums + epilogue (block-local E_tot, no atomics)
// sum(q)=0 per graph exactly (constraint row), so the cross-graph "off"
// term is O(solver eps) and dropped -> graphs fully independent.
__global__ __launch_bounds__(1024, 1) void k_main(
    const int* __restrict__ ei, const float* __restrict__ elen,
    const float* __restrict__ node_attrs, const float* __restrict__ kappa,
    const float* __restrict__ ref_eta, const float* __restrict__ ref_log_sigma,
    const float* __restrict__ ref_A, const float* __restrict__ ref_B,
    const float* __restrict__ ref_C, const float* __restrict__ ref_D,
    const float* __restrict__ ref_mu, const float* __restrict__ short_e,
    const float* __restrict__ atomic_short, const float* __restrict__ nf_in,
    float* __restrict__ out) {
    __shared__ ull s_pack[4096];   // 32 KB per-graph cell table
    __shared__ float sL[64][65];   // factor
    __shared__ float sF[64][65];   // factor * Fc
    __shared__ float s_diag[64];
    __shared__ float s_q[64];
    __shared__ float s_ash[64];
    __shared__ float s_red[16];

    const int g = blockIdx.x;
    const int tid = threadIdx.x;
    const int lane = tid & 63;
    const int wv = tid >> 6;               // 0..15; rows wv*4..wv*4+3
    const float SQRT_PI = 1.7724538509055159f;
    const float th1 = tanhf(1.0f);
    const float c1 = th1 * th1 * th1;

    // ---- phase A: zero packed table; per-lane type/sigma --------------------
#pragma unroll
    for (int k = 0; k < 4; ++k) s_pack[tid + k * 1024] = 0ull;
    const float4 na = *(const float4*)(node_attrs + ((size_t)((g << 6) + lane) << 2));
    const int tj = type_of(na);
    const float sgj = __expf(ref_log_sigma[tj]);
    if (tid < 64) {                         // wave 0: lane == tid
        s_diag[tid] = ref_eta[tj] + 1.0f / (sgj * SQRT_PI);
        s_ash[tid] = atomic_short[(g << 6) + tid];
    }
    __syncthreads();

    // ---- phase B: src-only stream; gather dst/len on hit -> LDS atomicMax ---
    {
        const int4* src4 = (const int4*)ei;
#define SCAN_ONE(IV, EOFF)                                                     \
        if (((IV) >> 6) == g) {                                                \
            const int e_ = e0 + (EOFF);                                        \
            const int jv_ = ei[EDGES + e_];                                    \
            const ull rb_ = (ull)__float_as_uint(elen[e_]);                    \
            atomicMax(&s_pack[(((IV) & 63) << 6) + (jv_ & 63)],                \
                      ((ull)(unsigned)e_ << 32) | rb_);                        \
            atomicMax(&s_pack[((jv_ & 63) << 6) + ((IV) & 63)],                \
                      ((ull)(unsigned)(e_ + HALF) << 32) | rb_);               \
        }
#pragma unroll 4
        for (int b = tid; b < HALF / 4; b += 1024) {
            const int4 si = src4[b];
            const int e0 = b << 2;
            SCAN_ONE(si.x, 0)
            SCAN_ONE(si.y, 1)
            SCAN_ONE(si.z, 2)
            SCAN_ONE(si.w, 3)
        }
#undef SCAN_ONE
    }
    __syncthreads();

    // ---- phase C: build factor / factor*Fc; E2b row sums --------------------
    float e2b[4];
#pragma unroll
    for (int r = 0; r < 4; ++r) {
        const int row = (wv << 2) + r;
        const ull pk = s_pack[(row << 6) + lane];
        const int ti = __shfl(tj, row);
        const float sgi = __shfl(sgj, row);
        const float gam = sqrtf(sgi * sgi + sgj * sgj);
        const float R = (pk > 0ull) ? __uint_as_float((unsigned)pk) : 0.5f;
        const float rinv = __frcp_rn(R);
        const float factor = erff(R * (0.70710678118654752f / gam)) * rinv;
        const float fc = fcut(R, c1);
        sL[row][lane] = factor;
        sF[row][lane] = factor * fc;
        float e = 0.0f;
        if (row != lane) {
            int t4 = ti * 4 + tj;
            float r2 = rinv * rinv;
            float r6 = r2 * r2 * r2;
            e = (ref_A[t4] * __expf(ref_B[t4] * (ref_mu[t4] - R)) -
                 ref_C[t4] * r6 - ref_D[t4] * (r6 * r2)) * fc;
        }
        e2b[r] = e;
    }
#pragma unroll
    for (int m = 1; m < 64; m <<= 1) {
#pragma unroll
        for (int r = 0; r < 4; ++r) e2b[r] += __shfl_xor(e2b[r], m);
    }
    __syncthreads();

    // ---- phase D: wave 0 solves (fp64); waves 1-15 copy node_feats ----------
    if (wv == 0) {
        const int i = tid;
        double Ld = (double)(s_diag[i] + sL[i][i]);
        double inv = 1.0 / Ld;
        double au = 1.0;
        double av = (double)kappa[(g << 6) + i];
        double my_u = 0.0, my_v = 0.0;
        for (int j = 0; j < 64; ++j) {
            double ij = bcast_d(inv, j);
            double uj = bcast_d(au, j) * ij;
            double vj = bcast_d(av, j) * ij;
            if (i == j) { my_u = uj; my_v = vj; }
            if (i > j) {
                double Lij = (double)sL[i][j];
                au -= Lij * uj;
                av -= Lij * vj;
            }
        }
        double Su = wave_sum_d(my_u);
        double Sv = wave_sum_d(my_v);
        double lam = Sv / Su;  // q = -v + (Sv/Su)u  => sum(q) = 0
        s_q[i] = (float)(-my_v + lam * my_u);
    } else {
        // 4096 float2 per graph (64 rows x 64 float2), 960 threads
        for (int t2 = tid - 64; t2 < 4096; t2 += 960) {
            int row = t2 >> 6, c = t2 & 63;
            float2 v = ((const float2*)nf_in)[(((g << 6) + row) << 6) + c];
            *(float2*)(out + OUT_NF + (size_t)((g << 6) + row) * 130 + c * 2) = v;
        }
    }
    __syncthreads();

    // ---- phase E: matvec row sums + epilogue --------------------------------
    const float qj = s_q[lane];
    float pr[4], wr[4];
#pragma unroll
    for (int r = 0; r < 4; ++r) {
        const int row = (wv << 2) + r;
        pr[r] = sF[row][lane] * qj;
        wr[r] = sL[row][lane] * qj;
    }
#pragma unroll
    for (int m = 1; m < 64; m <<= 1) {
#pragma unroll
        for (int r = 0; r < 4; ++r) {
            pr[r] += __shfl_xor(pr[r], m);
            wr[r] += __shfl_xor(wr[r], m);
        }
    }
    float acc = 0.0f;
#pragma unroll
    for (int r = 0; r < 4; ++r) {
        const int row = (wv << 2) + r;
        const float q = s_q[row];
        const float sgi = __shfl(sgj, row);
        if (lane == 0) {
            float coef = 0.5f / (sgi * SQRT_PI);
            float aEel = q * (wr[r] + coef * q);
            float e2 = 0.5f * e2b[r];
            out[OUT_NODEE + (g << 6) + row] = aEel + e2 + s_ash[row];
            out[OUT_Q + (g << 6) + row] = q;
            size_t nfb = OUT_NF + (size_t)((g << 6) + row) * 130;
            out[nfb + 128] = q;
            out[nfb + 129] = pr[r];
            acc += aEel + e2;
        }
    }
    if (lane == 0) s_red[wv] = acc;
    __syncthreads();
    if (tid == 0) {
        float s = 0.0f;
#pragma unroll
        for (int k = 0; k < 16; ++k) s += s_red[k];
        out[OUT_ETOT + g] = s + short_e[g];
    }
}

extern "C" void kernel_launch(void* const* d_in, const int* in_sizes, int n_in,
                              void* d_out, int out_size, void* d_ws, size_t ws_size,
                              hipStream_t stream) {
    const float* node_attrs = (const float*)d_in[1];
    const int* edge_index = (const int*)d_in[2];
    const float* edge_length = (const float*)d_in[3];
    const float* kappa = (const float*)d_in[4];
    const float* node_feats = (const float*)d_in[5];
    const float* ref_eta = (const float*)d_in[6];
    const float* ref_log_sigma = (const float*)d_in[7];
    const float* ref_A = (const float*)d_in[8];
    const float* ref_B = (const float*)d_in[9];
    const float* ref_C = (const float*)d_in[10];
    const float* ref_D = (const float*)d_in[11];
    const float* ref_mu = (const float*)d_in[12];
    const float* short_energy = (const float*)d_in[13];
    const float* atomic_short = (const float*)d_in[14];

    k_main<<<G, 1024, 0, stream>>>(edge_index, edge_length, node_attrs, kappa,
                                   ref_eta, ref_log_sigma, ref_A, ref_B, ref_C,
                                   ref_D, ref_mu, short_energy, atomic_short,
                                   node_feats, (float*)d_out);
}